// Round 18
// baseline (46.116 us; speedup 1.0000x reference)
//
#include <hip/hip_runtime.h>

// Deformable depthwise conv1d (fp32 in/out), MI355X.
// Round 18: R15 math + F16-PACKED LDS ROW. All hot math is already f16;
// storing the row as h2 pairs halves LDS bytes, turns the stride-16B b128
// reads (4.73M conflict cycles) into stride-8B b64 reads (2-way alias =
// free), and deletes the per-iter cvt_pkrtz chain (odd pairs come straight
// from LDS; even pairs via 1 v_alignbit each).
//   hrow[p] = {x[2(p-8)], x[2(p-8)+1]} (f16), zeros in 8-pair halos
//   Wpk[2m+1] = P[m+2]; Wpk[2m] = alignbit(P[m+2], P[m+1], 16)
//   conv/stencil/acc: R15 verbatim (packed pk_fma, SGPR weight splats)
// Fallback (any |offs|>1, ~never taken): exact f32 path entirely from global.

constexpr int B_ = 8;
constexpr int C_ = 512;
constexpr int T_ = 4096;
constexpr int K_ = 7;
constexpr int T_OUT = T_ - K_ + 1;      // 4090
constexpr int BLOCK = 256;
constexpr int NOUT = 4;                 // consecutive outputs per thread
constexpr int SPAN = NOUT * BLOCK;      // 1024 t per iter
constexpr int NIT = 4;
constexpr int PADP = 8;                 // halo pairs (16 halves) each side
constexpr int PAIRS = PADP + T_ / 2 + PADP;   // 2064 pairs = 8256 B

using h2 = decltype(__builtin_amdgcn_cvt_pkrtz(0.0f, 0.0f));  // <2 x half>

__device__ __forceinline__ unsigned alignbit16(unsigned hi, unsigned lo) {
#if __has_builtin(__builtin_amdgcn_alignbit)
    return __builtin_amdgcn_alignbit(hi, lo, 16);
#else
    return (unsigned)((((unsigned long long)hi << 32) | lo) >> 16);
#endif
}

// wave-uniform f32 -> packed-f16 splat, forced into an SGPR
__device__ __forceinline__ h2 uni_h2(float v) {
    h2 p = __builtin_amdgcn_cvt_pkrtz(v, v);
    int i = __builtin_bit_cast(int, p);
    i = __builtin_amdgcn_readfirstlane(i);
    return __builtin_bit_cast(h2, i);
}

__global__ __launch_bounds__(BLOCK)
void deform_dwconv1d_kernel(const float* __restrict__ x,
                            const float* __restrict__ weight,
                            const float* __restrict__ offset_w,
                            const float* __restrict__ offset_b,
                            float* __restrict__ out)
{
    __shared__ unsigned hrow[PAIRS];    // h2-packed row, 8.3 KB

    const int bc  = blockIdx.x;        // b*C + c
    const int c   = bc & (C_ - 1);
    const int tid = threadIdx.x;

    // zero halos (8 pairs front, 8 pairs back)
    if (tid < PADP) {
        hrow[tid] = 0u;
        hrow[PADP + T_ / 2 + tid] = 0u;
    }

    const float* xrow = x + (size_t)bc * T_;

    // stage: float4 global read -> 2 cvt_pkrtz -> ds_write_b64 (stride-8B)
    const float4* src = reinterpret_cast<const float4*>(xrow);
    #pragma unroll
    for (int i = 0; i < T_ / 4 / BLOCK; ++i) {   // 4 iters
        const int q = tid + i * BLOCK;           // float4 index
        const float4 f = src[q];
        const h2 ha = __builtin_amdgcn_cvt_pkrtz(f.x, f.y);
        const h2 hb = __builtin_amdgcn_cvt_pkrtz(f.z, f.w);
        uint2 w;
        w.x = __builtin_bit_cast(unsigned, ha);
        w.y = __builtin_bit_cast(unsigned, hb);
        *reinterpret_cast<uint2*>(&hrow[PADP + 2 * q]) = w;
    }

    // packed (splat) f16 weights, wave-uniform -> SGPRs via readfirstlane
    const float* owb = offset_w + c * K_ * K_;
    h2 owp[K_][K_], ob2[K_], wgt2[K_];
    #pragma unroll
    for (int k = 0; k < K_; ++k) {
        #pragma unroll
        for (int j = 0; j < K_; ++j)
            owp[k][j] = uni_h2(owb[k * K_ + j]);
        ob2[k]  = uni_h2(offset_b[c * K_ + k]);
        wgt2[k] = uni_h2(weight[c * K_ + k]);
    }

    __syncthreads();

    float* orow = out + (size_t)bc * T_OUT;
    const h2 zero2 = __builtin_bit_cast(h2, 0);

    #pragma unroll
    for (int it = 0; it < NIT; ++it) {
        const int t0 = it * SPAN + tid * NOUT;   // multiple of 4, max 4092
        const int bp = PADP + t0 / 2 - 2;        // even; byte addr % 8 == 0

        // P[n] = {x[t0-4+2n], x[t0-3+2n]}, n=0..7 : 4x ds_read_b64,
        // lane stride 8B -> 2-way bank alias (free)
        const uint2 q0 = *reinterpret_cast<const uint2*>(&hrow[bp]);
        const uint2 q1 = *reinterpret_cast<const uint2*>(&hrow[bp + 2]);
        const uint2 q2 = *reinterpret_cast<const uint2*>(&hrow[bp + 4]);
        const uint2 q3 = *reinterpret_cast<const uint2*>(&hrow[bp + 6]);
        const unsigned P[8] = {q0.x, q0.y, q1.x, q1.y, q2.x, q2.y, q3.x, q3.y};

        // Wpk[i] = {x[t0-1+i], x[t0+i]}, i=0..10
        h2 Wpk[11];
        #pragma unroll
        for (int m = 0; m <= 4; ++m)            // odd i: direct
            Wpk[2 * m + 1] = __builtin_bit_cast(h2, P[m + 2]);
        #pragma unroll
        for (int m = 0; m <= 5; ++m)            // even i: 1 alignbit
            Wpk[2 * m] = __builtin_bit_cast(h2, alignbit16(P[m + 2], P[m + 1]));

        // packed differences Epk[i] = Wpk[i] - Wpk[i+1]
        h2 Epk[10];
        #pragma unroll
        for (int i = 0; i < 10; ++i)
            Epk[i] = Wpk[i] - Wpk[i + 1];

        h2 acc01 = zero2, acc23 = zero2, bad2 = zero2;

        #pragma unroll
        for (int k = 0; k < K_; ++k) {
            // packed offset conv: o_r = ob + sum_j x[t0+r+j]*ow[k][j]
            // {x[t0+j+r], x[t0+j+r+1]} = Wpk[j+1+r]
            h2 o01 = ob2[k], o23 = ob2[k];
            #pragma unroll
            for (int j = 0; j < K_; ++j) {
                o01 = __builtin_elementwise_fma(Wpk[j + 1], owp[k][j], o01);
                o23 = __builtin_elementwise_fma(Wpk[j + 3], owp[k][j], o23);
            }

            bad2 = __builtin_elementwise_max(bad2, __builtin_elementwise_abs(o01));
            bad2 = __builtin_elementwise_max(bad2, __builtin_elementwise_abs(o23));

            // packed branchless 3-tap stencil (exact for |o| <= 1):
            // s_r = x[t0+r+k] + an*E_left - cn*E_right
            const h2 an01 = __builtin_elementwise_max(-o01, zero2);
            const h2 cn01 = __builtin_elementwise_max(o01, zero2);
            const h2 an23 = __builtin_elementwise_max(-o23, zero2);
            const h2 cn23 = __builtin_elementwise_max(o23, zero2);

            h2 s01 = __builtin_elementwise_fma(an01, Epk[k],      Wpk[k + 1]);
            s01    = __builtin_elementwise_fma(cn01, -Epk[k + 1], s01);
            h2 s23 = __builtin_elementwise_fma(an23, Epk[k + 2],  Wpk[k + 3]);
            s23    = __builtin_elementwise_fma(cn23, -Epk[k + 3], s23);

            acc01 = __builtin_elementwise_fma(wgt2[k], s01, acc01);
            acc23 = __builtin_elementwise_fma(wgt2[k], s23, acc23);
        }

        float acc[NOUT] = {(float)acc01.x, (float)acc01.y,
                           (float)acc23.x, (float)acc23.y};

        // exact fallback (wave-uniform, ~never taken): any |offs| > 1 ->
        // full f32 recompute from GLOBAL (validity-masked gathers,
        // reference semantics: zero outside [0, T-1]).
        const float badf = fmaxf((float)bad2.x, (float)bad2.y);
        if (__any(badf > 1.0f)) {
            #pragma unroll
            for (int r = 0; r < NOUT; ++r) {
                float a2 = 0.0f;
                #pragma unroll
                for (int k = 0; k < K_; ++k) {
                    float v = offset_b[c * K_ + k];
                    #pragma unroll
                    for (int j = 0; j < K_; ++j) {
                        const int xi = min(t0 + r + j, T_ - 1);  // only clamps
                        v = fmaf(xrow[xi], owb[k * K_ + j], v);  // discarded rows
                    }
                    const float pos = (float)(t0 + r + k) + v;
                    const float fl  = floorf(pos);
                    const int   i0  = (int)fl;
                    const float u   = pos - fl;
                    const int c0 = min(max(i0, 0), T_ - 1);
                    const int c1 = min(max(i0 + 1, 0), T_ - 1);
                    float g0 = xrow[c0];
                    float g1 = xrow[c1];
                    if (i0 < 0 || i0 > T_ - 1) g0 = 0.0f;
                    if (i0 + 1 < 0 || i0 + 1 > T_ - 1) g1 = 0.0f;
                    a2 = fmaf(fmaf(u, g1 - g0, g0), weight[c * K_ + k], a2);
                }
                acc[r] = a2;
            }
        }

        // stores: two 8B-aligned float2 per thread; guards only in the tail
        if (it < NIT - 1) {
            *reinterpret_cast<float2*>(orow + t0)     = make_float2(acc[0], acc[1]);
            *reinterpret_cast<float2*>(orow + t0 + 2) = make_float2(acc[2], acc[3]);
        } else {
            if (t0 + 1 < T_OUT)
                *reinterpret_cast<float2*>(orow + t0)     = make_float2(acc[0], acc[1]);
            if (t0 + 3 < T_OUT)
                *reinterpret_cast<float2*>(orow + t0 + 2) = make_float2(acc[2], acc[3]);
        }
    }
}

extern "C" void kernel_launch(void* const* d_in, const int* in_sizes, int n_in,
                              void* d_out, int out_size, void* d_ws, size_t ws_size,
                              hipStream_t stream) {
    const float* x        = (const float*)d_in[0];
    const float* weight   = (const float*)d_in[1];
    const float* offset_w = (const float*)d_in[2];
    const float* offset_b = (const float*)d_in[3];
    float* out = (float*)d_out;

    deform_dwconv1d_kernel<<<B_ * C_, BLOCK, 0, stream>>>(
        x, weight, offset_w, offset_b, out);
}